// Round 8
// baseline (437.309 us; speedup 1.0000x reference)
//
#include <hip/hip_runtime.h>
#include <stdint.h>

typedef float f32x4 __attribute__((ext_vector_type(4)));
typedef short s16x8 __attribute__((ext_vector_type(8)));
typedef unsigned u32x4 __attribute__((ext_vector_type(4)));

#define B_SZ 256
#define A_RG 196
#define DVD  2048
#define RNN  1024
#define H_SZ 512
#define M_TOT (B_SZ * A_RG)   // 50176 flat rows
#define BM 64
#define BN 128
#define BK 32
#define KT (DVD / BK)         // 64
#define NMT (M_TOT / BM)      // 784 m-tiles
#define NGRID (NMT * 4)       // 3136 blocks

__device__ __forceinline__ unsigned short f2bf(float f) {
    unsigned u = __builtin_bit_cast(unsigned, f);
    u = u + 0x7FFFu + ((u >> 16) & 1u);   // RNE
    return (unsigned short)(u >> 16);
}

__device__ __forceinline__ unsigned cvt2(float a, float b) {
    unsigned r;
    asm("v_cvt_pk_bf16_f32 %0, %1, %2" : "=v"(r) : "v"(a), "v"(b));
    return r;
}

__device__ __forceinline__ void gll16(const void* g, void* l) {
    __builtin_amdgcn_global_load_lds(
        (const __attribute__((address_space(1))) void*)g,
        (__attribute__((address_space(3))) void*)l, 16, 0, 0);
}

// ---------------------------------------------------------------------------
// Kernel 1: W_v [2048,512] fp32 -> Wt3 bf16 [kt 64][nc 4][col 128][k 32]:
// each (kt,nc) B-slab is a contiguous 8 KB block (one coalesced gll stage).
// Within a col's 32-k row, 8-elem chunk ch stored at ch ^ ((lc>>1)&3)
// (pre-swizzle matching the conflict-free ds_read pattern).
// ---------------------------------------------------------------------------
__global__ __launch_bounds__(256) void k_prepW(const float* __restrict__ Wv,
                                               unsigned short* __restrict__ Wt3) {
    __shared__ float tile[64][65];
    int kt = blockIdx.x >> 3, ct = blockIdx.x & 7;
    int k0 = kt * 64, c0 = ct * 64;
    int t = threadIdx.x;
    int cl = t & 63, rq = t >> 6;
#pragma unroll
    for (int i = 0; i < 16; ++i) {
        int r = rq * 16 + i;
        tile[r][cl] = Wv[(size_t)(k0 + r) * H_SZ + c0 + cl];
    }
    __syncthreads();
    int kl = t & 63;
#pragma unroll
    for (int i = 0; i < 16; ++i) {
        int cr = rq * 16 + i;
        int col = c0 + cr;
        int k = k0 + kl;
        int nc = col >> 7, lc = col & 127;
        int chs = ((k >> 3) & 3) ^ ((lc >> 1) & 3);
        size_t dst = (size_t)(k >> 5) * (4 * 128 * 32)
                   + (size_t)nc * (128 * 32)
                   + (size_t)lc * 32 + chs * 8 + (k & 7);
        Wt3[dst] = f2bf(tile[kl][cr]);
    }
}

// ---------------------------------------------------------------------------
// Kernel 2: base[b,h] = h_att[b]@W_ha + prev_h2[b]@W_hv + b_ha + b_hv + b_v
// ---------------------------------------------------------------------------
__global__ __launch_bounds__(256) void k_base(const float* __restrict__ h_att,
                                              const float* __restrict__ prev_h2,
                                              const float* __restrict__ W_ha,
                                              const float* __restrict__ b_ha,
                                              const float* __restrict__ W_hv,
                                              const float* __restrict__ b_hv,
                                              const float* __restrict__ b_v,
                                              float* __restrict__ base_g) {
    __shared__ float ha_s[4][RNN];
    __shared__ float pv_s[4][RNN];
    int bg = blockIdx.x >> 2, hg = blockIdx.x & 3;
    int t = threadIdx.x;
#pragma unroll
    for (int i = 0; i < 16; ++i) {
        int idx = i * 256 + t;
        int bl = idx >> 10, k = idx & 1023;
        ha_s[bl][k] = h_att[(size_t)(bg * 4 + bl) * RNN + k];
        pv_s[bl][k] = prev_h2[(size_t)(bg * 4 + bl) * RNN + k];
    }
    __syncthreads();
    int h = hg * 128 + (t & 127);
    int br = t >> 7;
    float aA0 = 0, aA1 = 0, aV0 = 0, aV1 = 0;
#pragma unroll 4
    for (int k = 0; k < RNN; ++k) {
        float w1 = W_ha[(size_t)k * H_SZ + h];
        float w2 = W_hv[(size_t)k * H_SZ + h];
        aA0 = fmaf(ha_s[br * 2][k],     w1, aA0);
        aA1 = fmaf(ha_s[br * 2 + 1][k], w1, aA1);
        aV0 = fmaf(pv_s[br * 2][k],     w2, aV0);
        aV1 = fmaf(pv_s[br * 2 + 1][k], w2, aV1);
    }
    float bias = b_ha[h] + b_hv[h] + b_v[h];
    base_g[(size_t)(bg * 4 + br * 2) * H_SZ + h]     = aA0 + aV0 + bias;
    base_g[(size_t)(bg * 4 + br * 2 + 1) * H_SZ + h] = aA1 + aV1 + bias;
}

// ---------------------------------------------------------------------------
// Kernel 3: N-split flat-M GEMM: block = 64 rows x 128 cols x K=2048,
// 256 thr = 4 waves (2M x 2N, wave 32x64, acc[2][4] = 32 VGPR).
// All staging via gll (A fp32 src-pre-swizzled, B pre-swizzled in Wt3,
// 8 KB contiguous per (kt,nc)). 2-deep pipeline, vmcnt(4), 2 barriers/step.
// LDS 33 KB, ~100 VGPR -> 4 blocks/CU (16 independent waves).
// XCD-cluster swizzle: 4 nc-siblings of an mtile land on the same XCD
// (xcd = d%8 is invariant over nc) -> A tile fetched once per XCD.
// Output: att4[nc][m] partial scores (relu is per-h, so h-chunk partials
// are exact); combined in k_ws.
// ---------------------------------------------------------------------------
__global__ __launch_bounds__(256, 4) void k_gemm(const float* __restrict__ imgs,
                                                 const unsigned short* __restrict__ Wt3,
                                                 const float* __restrict__ base_g,
                                                 const float* __restrict__ W_f,
                                                 float* __restrict__ att4) {
    __shared__ __align__(16) float A_s[2][BM * BK];   // 2 x 8 KB fp32, swizzled
    __shared__ __align__(16) short B_s[2][BN * BK];   // 2 x 8 KB bf16, swizzled
    __shared__ float att_part[2][BM];

    const int d = blockIdx.x;
    const int mtile = (d & 7) | ((d >> 5) << 3);   // [0,784)
    const int nc = (d >> 3) & 3;
    const int m0 = mtile * BM;
    const int n0 = nc * BN;
    const int t = threadIdx.x;
    const int lane = t & 63, w = t >> 6;

    // ---- A staging: 8 slabs of 1 KB (8 rows x 128 B); wave w: slabs w*2+i.
    // lane l -> row slab*8 + (l>>3); LDS chunk l&7 holds global chunk
    // (l&7)^(row&7) (inverse of the read swizzle).
    const unsigned aRow[2] = { (unsigned)(w * 16 + (lane >> 3)),
                               (unsigned)(w * 16 + 8 + (lane >> 3)) };
    unsigned aSrc[2], aLds[2];
#pragma unroll
    for (int i = 0; i < 2; ++i) {
        aSrc[i] = aRow[i] * (DVD * 4) + (((lane & 7) ^ (lane >> 3)) << 4);
        aLds[i] = (w * 2 + i) * 1024 + lane * 16;
    }
    const char* Abase = (const char*)(imgs + (size_t)m0 * DVD);
    // ---- B staging: 8 KB contiguous slab per (kt,nc); wave w: 2 x 1 KB.
    const char* Bbase = (const char*)Wt3 + (size_t)nc * 8192
                      + (size_t)(w * 2) * 1024 + (size_t)lane * 16;
    const unsigned bLds = (unsigned)(w * 2) * 1024 + lane * 16;

    auto stage = [&](int buf, int kt) {
        char* Ab = (char*)A_s[buf];
        char* Bb = (char*)B_s[buf];
#pragma unroll
        for (int i = 0; i < 2; ++i)
            gll16(Abase + (size_t)aSrc[i] + (size_t)kt * 128, Ab + aLds[i]);
#pragma unroll
        for (int i = 0; i < 2; ++i)
            gll16(Bbase + (size_t)kt * 32768 + i * 1024, Bb + bLds + i * 1024);
    };

    // ---- fragment read addresses ----
    const int wm = w >> 1, wn = w & 1;
    const int lr = lane & 15, g = lane >> 4;
    unsigned aLo[2], aHi[2], bAddr[4];
#pragma unroll
    for (int m = 0; m < 2; ++m) {
        int r = wm * 32 + m * 16 + lr;
        aLo[m] = (unsigned)(r * 128 + (((2 * g) ^ (r & 7)) << 4));
        aHi[m] = (unsigned)(r * 128 + (((2 * g + 1) ^ (r & 7)) << 4));
    }
#pragma unroll
    for (int n = 0; n < 4; ++n) {
        int c = wn * 64 + n * 16 + lr;
        bAddr[n] = (unsigned)(c * 64 + ((g ^ ((c >> 1) & 3)) << 4));
    }

    f32x4 acc[2][4] = {};

    auto compute = [&](int buf) {
        const char* Ac = (const char*)A_s[buf];
        const char* Bc = (const char*)B_s[buf];
        s16x8 bfr[4];
#pragma unroll
        for (int n = 0; n < 4; ++n) bfr[n] = *(const s16x8*)(Bc + bAddr[n]);
#pragma unroll
        for (int m = 0; m < 2; ++m) {
            f32x4 lo = *(const f32x4*)(Ac + aLo[m]);
            f32x4 hi = *(const f32x4*)(Ac + aHi[m]);
            u32x4 p;
            p[0] = cvt2(lo[0], lo[1]);
            p[1] = cvt2(lo[2], lo[3]);
            p[2] = cvt2(hi[0], hi[1]);
            p[3] = cvt2(hi[2], hi[3]);
            s16x8 af = __builtin_bit_cast(s16x8, p);
            __builtin_amdgcn_s_setprio(1);
#pragma unroll
            for (int n = 0; n < 4; ++n)
                acc[m][n] = __builtin_amdgcn_mfma_f32_16x16x32_bf16(
                    af, bfr[n], acc[m][n], 0, 0, 0);
            __builtin_amdgcn_s_setprio(0);
        }
    };

    // ---- pipelined K loop: 2-deep, counted vmcnt(4), 2 raw barriers/step --
    stage(0, 0);
    for (int kt = 0; kt < KT; ++kt) {
        if (kt < KT - 1) {
            stage((kt + 1) & 1, kt + 1);
            asm volatile("s_waitcnt vmcnt(4)" ::: "memory");  // tile kt landed
        } else {
            asm volatile("s_waitcnt vmcnt(0)" ::: "memory");
        }
        __builtin_amdgcn_sched_barrier(0);
        __builtin_amdgcn_s_barrier();       // tile kt visible to all waves
        compute(kt & 1);
        __builtin_amdgcn_s_barrier();       // readers done before re-stage
    }

    // ---- epilogue: partial att over this block's 128 h-cols ----
    const int b0 = m0 / A_RG;
    const int b1 = min(b0 + 1, B_SZ - 1);
    float wfv[4], bs0[4], bs1[4];
#pragma unroll
    for (int n = 0; n < 4; ++n) {
        int col = n0 + wn * 64 + n * 16 + lr;
        wfv[n] = W_f[col];
        bs0[n] = base_g[(size_t)b0 * H_SZ + col];
        bs1[n] = base_g[(size_t)b1 * H_SZ + col];
    }
#pragma unroll
    for (int m = 0; m < 2; ++m) {
        float pj[4] = {0.f, 0.f, 0.f, 0.f};
#pragma unroll
        for (int j = 0; j < 4; ++j) {
            int row = wm * 32 + m * 16 + g * 4 + j;
            bool second = (m0 + row) >= (b0 + 1) * A_RG;
#pragma unroll
            for (int n = 0; n < 4; ++n) {
                float bsv = second ? bs1[n] : bs0[n];
                pj[j] += fmaxf(acc[m][n][j] + bsv, 0.f) * wfv[n];
            }
        }
#pragma unroll
        for (int j = 0; j < 4; ++j) {
            float s = pj[j];
            s += __shfl_xor(s, 1);
            s += __shfl_xor(s, 2);
            s += __shfl_xor(s, 4);
            s += __shfl_xor(s, 8);     // sum over the 16 lr-lanes of this row
            if (lr == 0) {
                int row = wm * 32 + m * 16 + g * 4 + j;
                att_part[wn][row] = s;  // unique writer per (wn,row)
            }
        }
    }
    __syncthreads();

    if (t < BM)
        att4[(size_t)nc * M_TOT + m0 + t] = att_part[0][t] + att_part[1][t];
}

// ---------------------------------------------------------------------------
// Kernel 4: combine 4 n-chunk partials -> softmax over A=196 -> weighted sum.
// grid (2 d-halves, 256 b), block 256; thread t owns one f32x4 col group.
// ---------------------------------------------------------------------------
__global__ __launch_bounds__(256) void k_ws(const float* __restrict__ imgs,
                                            const float* __restrict__ att4,
                                            float* __restrict__ out) {
    __shared__ float alpha_s[A_RG];
    int b = blockIdx.y, dc = blockIdx.x;
    int t = threadIdx.x;

    if (t < 64) {
        float v[4], e[4];
        float mx = -1e30f;
#pragma unroll
        for (int i = 0; i < 4; ++i) {
            int r = i * 64 + t;
            if (r < A_RG) {
                size_t idx = (size_t)b * A_RG + r;
                v[i] = att4[idx] + att4[M_TOT + idx]
                     + att4[2 * (size_t)M_TOT + idx] + att4[3 * (size_t)M_TOT + idx];
            } else v[i] = -1e30f;
            mx = fmaxf(mx, v[i]);
        }
        for (int dd = 1; dd < 64; dd <<= 1) mx = fmaxf(mx, __shfl_xor(mx, dd));
        float sum = 0.f;
#pragma unroll
        for (int i = 0; i < 4; ++i) {
            int r = i * 64 + t;
            e[i] = (r < A_RG) ? __expf(v[i] - mx) : 0.f;
            sum += e[i];
        }
        for (int dd = 1; dd < 64; dd <<= 1) sum += __shfl_xor(sum, dd);
        float inv = 1.0f / sum;
#pragma unroll
        for (int i = 0; i < 4; ++i) {
            int r = i * 64 + t;
            if (r < A_RG) alpha_s[r] = e[i] * inv;
        }
    }
    __syncthreads();

    const float* ib = imgs + (size_t)b * A_RG * DVD + dc * 1024 + t * 4;
    f32x4 o0 = {}, o1 = {};
#pragma unroll 2
    for (int a = 0; a < A_RG; a += 2) {
        float al0 = alpha_s[a], al1 = alpha_s[a + 1];
        f32x4 v0 = *(const f32x4*)(ib + (size_t)a * DVD);
        f32x4 v1 = *(const f32x4*)(ib + (size_t)(a + 1) * DVD);
#pragma unroll
        for (int j = 0; j < 4; ++j) {
            o0[j] = fmaf(al0, v0[j], o0[j]);
            o1[j] = fmaf(al1, v1[j], o1[j]);
        }
    }
    f32x4 o;
#pragma unroll
    for (int j = 0; j < 4; ++j) o[j] = o0[j] + o1[j];
    *(f32x4*)(out + (size_t)b * DVD + dc * 1024 + t * 4) = o;
}

// ---------------------------------------------------------------------------
extern "C" void kernel_launch(void* const* d_in, const int* in_sizes, int n_in,
                              void* d_out, int out_size, void* d_ws, size_t ws_size,
                              hipStream_t stream) {
    const float* h_att   = (const float*)d_in[0];
    const float* prev_h2 = (const float*)d_in[1];
    const float* imgs    = (const float*)d_in[2];
    const float* W_v     = (const float*)d_in[3];
    const float* b_v     = (const float*)d_in[4];
    const float* W_ha    = (const float*)d_in[5];
    const float* b_ha    = (const float*)d_in[6];
    const float* W_hv    = (const float*)d_in[7];
    const float* b_hv    = (const float*)d_in[8];
    const float* W_f     = (const float*)d_in[9];
    // d_in[10] = b_f: softmax-invariant additive constant -> unused

    // ws layout: [0,2MB) Wt3 bf16 [64][4][128][32]; [2MB,2.5MB) base fp32
    // [256][512]; [2.5MB, +803KB) att4 fp32 [4][50176]
    unsigned short* Wt3 = (unsigned short*)d_ws;
    float* base_g = (float*)((char*)d_ws + (size_t)DVD * H_SZ * 2);
    float* att4   = (float*)((char*)d_ws + (size_t)DVD * H_SZ * 2 + (size_t)B_SZ * H_SZ * 4);
    float* out = (float*)d_out;

    hipLaunchKernelGGL(k_prepW, dim3(256), dim3(256), 0, stream, W_v, Wt3);
    hipLaunchKernelGGL(k_base, dim3(256), dim3(256), 0, stream,
                       h_att, prev_h2, W_ha, b_ha, W_hv, b_hv, b_v, base_g);
    hipLaunchKernelGGL(k_gemm, dim3(NGRID), dim3(256), 0, stream,
                       imgs, Wt3, base_g, W_f, att4);
    hipLaunchKernelGGL(k_ws, dim3(2, B_SZ), dim3(256), 0, stream,
                       imgs, att4, out);
}

// Round 9
// 350.694 us; speedup vs baseline: 1.2470x; 1.2470x over previous
//
#include <hip/hip_runtime.h>
#include <stdint.h>

typedef float f32x4 __attribute__((ext_vector_type(4)));
typedef short s16x8 __attribute__((ext_vector_type(8)));
typedef unsigned u32x4 __attribute__((ext_vector_type(4)));

#define B_SZ 256
#define A_RG 196
#define DVD  2048
#define RNN  1024
#define H_SZ 512
#define M_TOT (B_SZ * A_RG)   // 50176 flat rows
#define BM 128
#define BK 32
#define KT (DVD / BK)         // 64
#define NBLK (M_TOT / BM)     // 392 (divisible by 8 -> even XCD spread)

__device__ __forceinline__ unsigned short f2bf(float f) {
    unsigned u = __builtin_bit_cast(unsigned, f);
    u = u + 0x7FFFu + ((u >> 16) & 1u);   // RNE
    return (unsigned short)(u >> 16);
}

__device__ __forceinline__ unsigned cvt2(float a, float b) {
    unsigned r;
    asm("v_cvt_pk_bf16_f32 %0, %1, %2" : "=v"(r) : "v"(a), "v"(b));
    return r;
}

// ---------------------------------------------------------------------------
// Kernel 1: W_v [2048,512] fp32 -> Wt4 bf16 packed in MFMA-B-fragment order:
// 16B slot index = (kt*32 + frag)*64 + g*16 + lr, elem = k&7, where
// frag = col>>4, lr = col&15, kt = k>>5, g = (k>>3)&3. One wave B-frag load
// is then a CONTIGUOUS 1KB global_load_dwordx4 (lane l at slot base + l*16).
// ---------------------------------------------------------------------------
__global__ __launch_bounds__(256) void k_prepW(const float* __restrict__ Wv,
                                               unsigned short* __restrict__ Wt4) {
    __shared__ float tile[64][65];
    int kb = blockIdx.x >> 3, ct = blockIdx.x & 7;
    int k0 = kb * 64, c0 = ct * 64;
    int t = threadIdx.x;
    int cl = t & 63, rq = t >> 6;
#pragma unroll
    for (int i = 0; i < 16; ++i) {
        int r = rq * 16 + i;
        tile[r][cl] = Wv[(size_t)(k0 + r) * H_SZ + c0 + cl];
    }
    __syncthreads();
    int kl = t & 63;
#pragma unroll
    for (int i = 0; i < 16; ++i) {
        int cr = rq * 16 + i;
        int col = c0 + cr;
        int k = k0 + kl;
        int f = col >> 4, lr = col & 15;
        int kt = k >> 5, g = (k >> 3) & 3, e = k & 7;
        size_t dst = ((size_t)(kt * 32 + f) * 64 + g * 16 + lr) * 8 + e;
        Wt4[dst] = f2bf(tile[kl][cr]);
    }
}

// ---------------------------------------------------------------------------
// Kernel 2: base[b,h] = h_att[b]@W_ha + prev_h2[b]@W_hv + b_ha + b_hv + b_v
// ---------------------------------------------------------------------------
__global__ __launch_bounds__(256) void k_base(const float* __restrict__ h_att,
                                              const float* __restrict__ prev_h2,
                                              const float* __restrict__ W_ha,
                                              const float* __restrict__ b_ha,
                                              const float* __restrict__ W_hv,
                                              const float* __restrict__ b_hv,
                                              const float* __restrict__ b_v,
                                              float* __restrict__ base_g) {
    __shared__ float ha_s[4][RNN];
    __shared__ float pv_s[4][RNN];
    int bg = blockIdx.x >> 2, hg = blockIdx.x & 3;
    int t = threadIdx.x;
#pragma unroll
    for (int i = 0; i < 16; ++i) {
        int idx = i * 256 + t;
        int bl = idx >> 10, k = idx & 1023;
        ha_s[bl][k] = h_att[(size_t)(bg * 4 + bl) * RNN + k];
        pv_s[bl][k] = prev_h2[(size_t)(bg * 4 + bl) * RNN + k];
    }
    __syncthreads();
    int h = hg * 128 + (t & 127);
    int br = t >> 7;
    float aA0 = 0, aA1 = 0, aV0 = 0, aV1 = 0;
#pragma unroll 4
    for (int k = 0; k < RNN; ++k) {
        float w1 = W_ha[(size_t)k * H_SZ + h];
        float w2 = W_hv[(size_t)k * H_SZ + h];
        aA0 = fmaf(ha_s[br * 2][k],     w1, aA0);
        aA1 = fmaf(ha_s[br * 2 + 1][k], w1, aA1);
        aV0 = fmaf(pv_s[br * 2][k],     w2, aV0);
        aV1 = fmaf(pv_s[br * 2 + 1][k], w2, aV1);
    }
    float bias = b_ha[h] + b_hv[h] + b_v[h];
    base_g[(size_t)(bg * 4 + br * 2) * H_SZ + h]     = aA0 + aV0 + bias;
    base_g[(size_t)(bg * 4 + br * 2 + 1) * H_SZ + h] = aA1 + aV1 + bias;
}

// ---------------------------------------------------------------------------
// Kernel 3: flat-M GEMM [50176,2048]x[2048,512] -> fused relu(.+base)*W_f
// reduce -> att_g. 512 thr = 8 waves (2M x 4N, wave 64x128, acc[4][8]).
// B NEVER touches LDS: per-wave fragment loads are contiguous 1KB
// global_load_dwordx4 from L2-resident Wt4; bC0/bC1 reloaded right after
// their MFMA cluster (WAR enforces interleave; compiler emits counted
// vmcnt automatically). A: bf16 LDS dbuf (8KB x2), reg-staged 2 tiles ahead,
// ds_write placed after MFMA. ONE raw barrier/tile, lgkmcnt(0) only --
// vmem queue never drained.
// ---------------------------------------------------------------------------
__global__ __launch_bounds__(512, 2) void k_gemm(const float* __restrict__ imgs,
                                                 const unsigned short* __restrict__ Wt4,
                                                 const float* __restrict__ base_g,
                                                 const float* __restrict__ W_f,
                                                 float* __restrict__ att_g) {
    __shared__ __align__(16) short A_s[2][BM * BK];   // 2 x 8 KB bf16, swizzled
    __shared__ float att_part[4][BM];

    const int m0 = blockIdx.x * BM;
    const int t = threadIdx.x;
    const int lane = t & 63, w = t >> 6;
    const int wm = w >> 2, wn = w & 3;          // 2M x 4N wave grid
    const int lr = lane & 15, g = lane >> 4;

    // ---- A staging: thread t -> row t>>2, chunk t&3 (8 floats = 32B) ----
    const int arow = t >> 2, ac = t & 3;
    const char* Agp = (const char*)imgs + (size_t)(m0 + arow) * (DVD * 4) + ac * 32;
    const unsigned awr = (unsigned)(arow * 64 + ((ac ^ (arow & 3)) << 4));

    // ---- A fragment read addresses (swizzle: chunk g -> slot g^(r&3)) ----
    unsigned ard[4];
#pragma unroll
    for (int m = 0; m < 4; ++m) {
        int r = wm * 64 + m * 16 + lr;
        ard[m] = (unsigned)(r * 64 + ((g ^ (r & 3)) << 4));
    }

    // ---- B fragment base: frag n of wave -> (kt*32 + wn*8 + n)*1024 + lane*16
    const char* Bgp = (const char*)Wt4 + (size_t)(wn * 8) * 1024 + (size_t)lane * 16;

    f32x4 acc[4][8] = {};
    s16x8 bC0[4], bC1[4];
    float4 rE0, rE1, rO0, rO1;

    auto ldA = [&](int kt, float4& r0, float4& r1) {
        const char* p = Agp + kt * 128;
        r0 = *(const float4*)p;
        r1 = *(const float4*)(p + 16);
    };
    auto wrA = [&](int buf, const float4& r0, const float4& r1) {
        u32x4 p;
        p[0] = cvt2(r0.x, r0.y);
        p[1] = cvt2(r0.z, r0.w);
        p[2] = cvt2(r1.x, r1.y);
        p[3] = cvt2(r1.z, r1.w);
        *(s16x8*)((char*)A_s[buf] + awr) = __builtin_bit_cast(s16x8, p);
    };
    auto ldB0 = [&](int kt) {
#pragma unroll
        for (int n = 0; n < 4; ++n)
            bC0[n] = *(const s16x8*)(Bgp + (size_t)kt * 32768 + n * 1024);
    };
    auto ldB1 = [&](int kt) {
#pragma unroll
        for (int n = 0; n < 4; ++n)
            bC1[n] = *(const s16x8*)(Bgp + (size_t)kt * 32768 + (4 + n) * 1024);
    };
    auto bar = [&]() {
        __builtin_amdgcn_sched_barrier(0);
        asm volatile("s_waitcnt lgkmcnt(0)" ::: "memory");
        __builtin_amdgcn_s_barrier();
        __builtin_amdgcn_sched_barrier(0);
    };

    // ---- prologue: A(0),A(1) regs; B(0) regs; A(0) -> LDS buf0 ----
    ldA(0, rE0, rE1);
    ldA(1, rO0, rO1);
    ldB0(0); ldB1(0);
    wrA(0, rE0, rE1);
    bar();

    // ---- per tile: ldA(+2); ds_read af; MFMA(bC0); reload bC0(+1);
    //      MFMA(bC1); reload bC1(+1); cvt+ds_write A(+1); lgkm; barrier ----
#define TILE(KT_, RW0, RW1, RL0, RL1)                                          \
    {                                                                          \
        ldA((KT_) + 2, RL0, RL1);                                              \
        s16x8 af[4];                                                           \
        _Pragma("unroll")                                                      \
        for (int m = 0; m < 4; ++m)                                            \
            af[m] = *(const s16x8*)((char*)A_s[(KT_) & 1] + ard[m]);           \
        __builtin_amdgcn_s_setprio(1);                                         \
        _Pragma("unroll")                                                      \
        for (int m = 0; m < 4; ++m)                                            \
            _Pragma("unroll")                                                  \
            for (int n = 0; n < 4; ++n)                                        \
                acc[m][n] = __builtin_amdgcn_mfma_f32_16x16x32_bf16(           \
                    af[m], bC0[n], acc[m][n], 0, 0, 0);                        \
        __builtin_amdgcn_s_setprio(0);                                         \
        ldB0((KT_) + 1);                                                       \
        __builtin_amdgcn_s_setprio(1);                                         \
        _Pragma("unroll")                                                      \
        for (int m = 0; m < 4; ++m)                                            \
            _Pragma("unroll")                                                  \
            for (int n = 0; n < 4; ++n)                                        \
                acc[m][4 + n] = __builtin_amdgcn_mfma_f32_16x16x32_bf16(       \
                    af[m], bC1[n], acc[m][4 + n], 0, 0, 0);                    \
        __builtin_amdgcn_s_setprio(0);                                         \
        ldB1((KT_) + 1);                                                       \
        wrA(((KT_) + 1) & 1, RW0, RW1);                                        \
        bar();                                                                 \
    }

    for (int kt = 0; kt < KT - 2; kt += 2) {
        TILE(kt,     rO0, rO1, rE0, rE1);   // write A(kt+1), load A(kt+2)
        TILE(kt + 1, rE0, rE1, rO0, rO1);   // write A(kt+2), load A(kt+3)
    }
#undef TILE
    // tile 62: no further A loads; stage B(63); write A(63)
    {
        s16x8 af[4];
#pragma unroll
        for (int m = 0; m < 4; ++m)
            af[m] = *(const s16x8*)((char*)A_s[0] + ard[m]);
        __builtin_amdgcn_s_setprio(1);
#pragma unroll
        for (int m = 0; m < 4; ++m)
#pragma unroll
            for (int n = 0; n < 4; ++n)
                acc[m][n] = __builtin_amdgcn_mfma_f32_16x16x32_bf16(
                    af[m], bC0[n], acc[m][n], 0, 0, 0);
        __builtin_amdgcn_s_setprio(0);
        ldB0(KT - 1);
        __builtin_amdgcn_s_setprio(1);
#pragma unroll
        for (int m = 0; m < 4; ++m)
#pragma unroll
            for (int n = 0; n < 4; ++n)
                acc[m][4 + n] = __builtin_amdgcn_mfma_f32_16x16x32_bf16(
                    af[m], bC1[n], acc[m][4 + n], 0, 0, 0);
        __builtin_amdgcn_s_setprio(0);
        ldB1(KT - 1);
        wrA(1, rO0, rO1);
        bar();
    }
    // tile 63
    {
        s16x8 af[4];
#pragma unroll
        for (int m = 0; m < 4; ++m)
            af[m] = *(const s16x8*)((char*)A_s[1] + ard[m]);
        __builtin_amdgcn_s_setprio(1);
#pragma unroll
        for (int m = 0; m < 4; ++m)
#pragma unroll
            for (int n = 0; n < 4; ++n)
                acc[m][n] = __builtin_amdgcn_mfma_f32_16x16x32_bf16(
                    af[m], bC0[n], acc[m][n], 0, 0, 0);
#pragma unroll
        for (int m = 0; m < 4; ++m)
#pragma unroll
            for (int n = 0; n < 4; ++n)
                acc[m][4 + n] = __builtin_amdgcn_mfma_f32_16x16x32_bf16(
                    af[m], bC1[n], acc[m][4 + n], 0, 0, 0);
        __builtin_amdgcn_s_setprio(0);
    }

    // ---- epilogue: att[row] = sum_h relu(p + base[b(row),h]) * W_f[h] ----
    const int b0 = m0 / A_RG;
    const int b1 = min(b0 + 1, B_SZ - 1);
    float wfv[8], bs0[8], bs1[8];
#pragma unroll
    for (int n = 0; n < 8; ++n) {
        int col = wn * 128 + n * 16 + lr;
        wfv[n] = W_f[col];
        bs0[n] = base_g[(size_t)b0 * H_SZ + col];
        bs1[n] = base_g[(size_t)b1 * H_SZ + col];
    }
#pragma unroll
    for (int m = 0; m < 4; ++m) {
        float pj[4] = {0.f, 0.f, 0.f, 0.f};
#pragma unroll
        for (int j = 0; j < 4; ++j) {
            int row = wm * 64 + m * 16 + g * 4 + j;
            bool second = (m0 + row) >= (b0 + 1) * A_RG;
#pragma unroll
            for (int n = 0; n < 8; ++n) {
                float bsv = second ? bs1[n] : bs0[n];
                pj[j] += fmaxf(acc[m][n][j] + bsv, 0.f) * wfv[n];
            }
        }
#pragma unroll
        for (int j = 0; j < 4; ++j) {
            float s = pj[j];
            s += __shfl_xor(s, 1);
            s += __shfl_xor(s, 2);
            s += __shfl_xor(s, 4);
            s += __shfl_xor(s, 8);     // sum over the 16 lr-lanes of this row
            if (lr == 0) {
                int row = wm * 64 + m * 16 + g * 4 + j;
                att_part[wn][row] = s;  // unique writer per (wn,row)
            }
        }
    }
    __syncthreads();

    if (t < BM) {
        att_g[m0 + t] = att_part[0][t] + att_part[1][t] +
                        att_part[2][t] + att_part[3][t];
    }
}

// ---------------------------------------------------------------------------
// Kernel 4: softmax over A=196 + weighted sum. grid (2 d-halves, 256 b),
// 512 thr (8 waves -> 16 waves/CU at 2 blocks/CU); thread owns float2 col
// pair; 4 independent accumulators, unroll 4 for MLP.
// ---------------------------------------------------------------------------
__global__ __launch_bounds__(512) void k_ws(const float* __restrict__ imgs,
                                            const float* __restrict__ att_g,
                                            float* __restrict__ out) {
    __shared__ float alpha_s[A_RG + 4];
    int b = blockIdx.y, dc = blockIdx.x;
    int t = threadIdx.x;

    if (t < 64) {
        float v[4], e[4];
        float mx = -1e30f;
#pragma unroll
        for (int i = 0; i < 4; ++i) {
            int r = i * 64 + t;
            v[i] = (r < A_RG) ? att_g[(size_t)b * A_RG + r] : -1e30f;
            mx = fmaxf(mx, v[i]);
        }
        for (int d = 1; d < 64; d <<= 1) mx = fmaxf(mx, __shfl_xor(mx, d));
        float sum = 0.f;
#pragma unroll
        for (int i = 0; i < 4; ++i) {
            int r = i * 64 + t;
            e[i] = (r < A_RG) ? __expf(v[i] - mx) : 0.f;
            sum += e[i];
        }
        for (int d = 1; d < 64; d <<= 1) sum += __shfl_xor(sum, d);
        float inv = 1.0f / sum;
#pragma unroll
        for (int i = 0; i < 4; ++i) {
            int r = i * 64 + t;
            if (r < A_RG + 4) alpha_s[r] = (r < A_RG) ? e[i] * inv : 0.f;
        }
    }
    __syncthreads();

    const float2* ib = (const float2*)(imgs + (size_t)b * A_RG * DVD + dc * 1024) + t;
    float2 o0 = {0.f, 0.f}, o1 = {0.f, 0.f}, o2 = {0.f, 0.f}, o3 = {0.f, 0.f};
    for (int a = 0; a < A_RG; a += 4) {           // 196 = 49*4 exact
        float al0 = alpha_s[a],     al1 = alpha_s[a + 1];
        float al2 = alpha_s[a + 2], al3 = alpha_s[a + 3];
        float2 v0 = ib[(size_t)(a)     * (DVD / 2)];
        float2 v1 = ib[(size_t)(a + 1) * (DVD / 2)];
        float2 v2 = ib[(size_t)(a + 2) * (DVD / 2)];
        float2 v3 = ib[(size_t)(a + 3) * (DVD / 2)];
        o0.x = fmaf(al0, v0.x, o0.x); o0.y = fmaf(al0, v0.y, o0.y);
        o1.x = fmaf(al1, v1.x, o1.x); o1.y = fmaf(al1, v1.y, o1.y);
        o2.x = fmaf(al2, v2.x, o2.x); o2.y = fmaf(al2, v2.y, o2.y);
        o3.x = fmaf(al3, v3.x, o3.x); o3.y = fmaf(al3, v3.y, o3.y);
    }
    float2 o = {o0.x + o1.x + o2.x + o3.x, o0.y + o1.y + o2.y + o3.y};
    ((float2*)(out + (size_t)b * DVD + dc * 1024))[t] = o;
}

// ---------------------------------------------------------------------------
extern "C" void kernel_launch(void* const* d_in, const int* in_sizes, int n_in,
                              void* d_out, int out_size, void* d_ws, size_t ws_size,
                              hipStream_t stream) {
    const float* h_att   = (const float*)d_in[0];
    const float* prev_h2 = (const float*)d_in[1];
    const float* imgs    = (const float*)d_in[2];
    const float* W_v     = (const float*)d_in[3];
    const float* b_v     = (const float*)d_in[4];
    const float* W_ha    = (const float*)d_in[5];
    const float* b_ha    = (const float*)d_in[6];
    const float* W_hv    = (const float*)d_in[7];
    const float* b_hv    = (const float*)d_in[8];
    const float* W_f     = (const float*)d_in[9];
    // d_in[10] = b_f: softmax-invariant additive constant -> unused

    // ws layout: [0,2MB) Wt4 bf16 fragment-packed; [2MB,+512KB) base fp32
    // [256][512]; then att fp32 [50176]
    unsigned short* Wt4 = (unsigned short*)d_ws;
    float* base_g = (float*)((char*)d_ws + (size_t)DVD * H_SZ * 2);
    float* att_g  = (float*)((char*)d_ws + (size_t)DVD * H_SZ * 2 + (size_t)B_SZ * H_SZ * 4);
    float* out = (float*)d_out;

    hipLaunchKernelGGL(k_prepW, dim3(256), dim3(256), 0, stream, W_v, Wt4);
    hipLaunchKernelGGL(k_base, dim3(256), dim3(256), 0, stream,
                       h_att, prev_h2, W_ha, b_ha, W_hv, b_hv, b_v, base_g);
    hipLaunchKernelGGL(k_gemm, dim3(NBLK), dim3(512), 0, stream,
                       imgs, Wt4, base_g, W_f, att_g);
    hipLaunchKernelGGL(k_ws, dim3(2, B_SZ), dim3(512), 0, stream,
                       imgs, att_g, out);
}